// Round 11
// baseline (5153.413 us; speedup 1.0000x reference)
//
#include <hip/hip_runtime.h>

#define NN 100000
#define NE 1600000
#define NB_N ((NN + 255) / 256)
#define NB_E ((NE + 255) / 256)
#define NB_G ((NN + 31) / 32)   // 8-lane-group kernels: 32 nodes per 256-thr block

// nontemporal pair load: bypasses L2 allocation for the zero-reuse edge stream
__device__ __forceinline__ void nt_pair(const int2* p, int& src, float& w) {
    unsigned long long v = __builtin_nontemporal_load(
        reinterpret_cast<const unsigned long long*>(p));
    src = (int)(v & 0xffffffffull);
    w = __int_as_float((int)(v >> 32));
}

// ---------------- preprocessing: CSR build ----------------

__global__ void zero_kernel(int* __restrict__ cnt) {
    int i = blockIdx.x * 256 + threadIdx.x;
    if (i < NN) cnt[i] = 0;
}

__global__ void edge_pass1(const int* __restrict__ ei, int* __restrict__ cnt,
                           int* __restrict__ rank) {
    int e = blockIdx.x * 256 + threadIdx.x;
    if (e < NE) {
        int col = ei[NE + e];
        rank[e] = atomicAdd(&cnt[col], 1);
    }
}

__global__ void scan_block(const int* __restrict__ cnt, int* __restrict__ colptr,
                           int* __restrict__ bsum) {
    __shared__ int s[256];
    int t = threadIdx.x;
    int i = blockIdx.x * 256 + t;
    int v = (i < NN) ? cnt[i] : 0;
    s[t] = v;
    __syncthreads();
    for (int off = 1; off < 256; off <<= 1) {
        int x = (t >= off) ? s[t - off] : 0;
        __syncthreads();
        s[t] += x;
        __syncthreads();
    }
    if (i < NN) colptr[i] = s[t] - v;
    if (t == 255) bsum[blockIdx.x] = s[255];
}

__global__ void scan_top(int* __restrict__ bsum, int nb) {
    __shared__ int s[512];
    int t = threadIdx.x;
    int v = (t < nb) ? bsum[t] : 0;
    s[t] = v;
    __syncthreads();
    for (int off = 1; off < 512; off <<= 1) {
        int x = (t >= off) ? s[t - off] : 0;
        __syncthreads();
        s[t] += x;
        __syncthreads();
    }
    if (t < nb) bsum[t] = s[t] - v;
}

__global__ void scan_add(int* __restrict__ colptr, const int* __restrict__ bsum) {
    int i = blockIdx.x * 256 + threadIdx.x;
    if (i < NN) colptr[i] += bsum[blockIdx.x];
    if (i == 0) colptr[NN] = NE;
}

__global__ void scatter_kernel(const int* __restrict__ ei, const float* __restrict__ ew,
                               const int* __restrict__ colptr, const int* __restrict__ rank,
                               int2* __restrict__ pairs) {
    int e = blockIdx.x * 256 + threadIdx.x;
    if (e < NE) {
        int r = ei[e], col = ei[NE + e];
        pairs[colptr[col] + rank[e]] = make_int2(r, __float_as_int(ew[e]));
    }
}

__global__ void deg_dis_kernel(const int2* __restrict__ pairs, const int* __restrict__ colptr,
                               float* __restrict__ dis) {
    int n = blockIdx.x * 256 + threadIdx.x;
    if (n < NN) {
        int e0 = colptr[n], e1 = colptr[n + 1];
        float d = 0.f;
        for (int e = e0; e < e1; e++) d += __int_as_float(pairs[e].y);
        dis[n] = d > 0.f ? (float)(1.0 / sqrt((double)d)) : 0.f;
    }
}

__global__ void rescale_kernel(int2* __restrict__ pairs, const int* __restrict__ colptr,
                               const float* __restrict__ dis) {
    int n = blockIdx.x * 256 + threadIdx.x;
    if (n < NN) {
        float dn = dis[n];
        int e0 = colptr[n], e1 = colptr[n + 1];
        for (int e = e0; e < e1; e++) {
            int2 p = pairs[e];
            pairs[e] = make_int2(p.x, __float_as_int(dis[p.x] * __int_as_float(p.y) * dn));
        }
    }
}

__global__ void build_x(const float* __restrict__ c, const int* __restrict__ ip,
                        float2* __restrict__ X1) {
    int n = blockIdx.x * 256 + threadIdx.x;
    if (n < NN) {
        float2 v;
        v.x = (n == ip[0]) ? 1.f : 0.f;
        v.y = c[n];
        X1[n] = v;
    }
}

// ---------------- layer 1: 2 -> 15, forward, 8-lane edge-split ----------------

__launch_bounds__(256)
__global__ void init_acc1(const float2* __restrict__ X1, const float* __restrict__ W1,
                          const float* __restrict__ b1, float* __restrict__ acc) {
    __shared__ float sW[30], sb[15];
    int t = threadIdx.x;
    if (t < 30) sW[t] = W1[t];
    if (t < 15) sb[t] = b1[t];
    __syncthreads();
    int n = blockIdx.x * 256 + t;
    if (n >= NN) return;
    float2 x = X1[n];
    float a[16];
#pragma unroll
    for (int j = 0; j < 15; j++) a[j] = fmaf(x.x, sW[j], fmaf(x.y, sW[15 + j], sb[j]));
    a[15] = 0.f;
    float4* o = reinterpret_cast<float4*>(acc + (size_t)n * 16);
#pragma unroll
    for (int q = 0; q < 4; q++) o[q] = make_float4(a[4*q], a[4*q+1], a[4*q+2], a[4*q+3]);
}

// propagate only (odd k): h_k = A h_{k-1}
__launch_bounds__(256)
__global__ void step1_prop(const int2* __restrict__ pairs, const int* __restrict__ colptr,
                           const float2* __restrict__ hin, float2* __restrict__ hout) {
    int t = threadIdx.x;
    int g = t >> 3, l = t & 7;
    int n = blockIdx.x * 32 + g;
    if (n >= NN) return;
    int e0 = colptr[n], e1 = colptr[n + 1];
    float h0 = 0.f, h1 = 0.f;
    for (int e = e0 + l; e < e1; e += 8) {
        int src; float w;
        nt_pair(&pairs[e], src, w);
        float2 v = hin[src];
        h0 = fmaf(w, v.x, h0);
        h1 = fmaf(w, v.y, h1);
    }
    h0 += __shfl_xor(h0, 1); h1 += __shfl_xor(h1, 1);
    h0 += __shfl_xor(h0, 2); h1 += __shfl_xor(h1, 2);
    h0 += __shfl_xor(h0, 4); h1 += __shfl_xor(h1, 4);
    if (l == 0) hout[n] = make_float2(h0, h1);
}

// propagate + double acc update (even k): acc += h_{k-1} W_{k-1} + h_k W_k
// Wpair points at W_{k-1}; W_k follows contiguously (+30).
__launch_bounds__(256)
__global__ void step1_acc(const int2* __restrict__ pairs, const int* __restrict__ colptr,
                          const float2* __restrict__ hin, float2* __restrict__ hout,
                          float* __restrict__ acc, const float* __restrict__ Wpair) {
    __shared__ float sWm[32], sWk[32];  // [2][16] padded, col 15 = 0
    int t = threadIdx.x;
    if (t < 32) {
        int f = t >> 4, j = t & 15;
        sWm[t] = (j < 15) ? Wpair[f * 15 + j] : 0.f;
        sWk[t] = (j < 15) ? Wpair[30 + f * 15 + j] : 0.f;
    }
    __syncthreads();
    int g = t >> 3, l = t & 7;
    int n = blockIdx.x * 32 + g;
    if (n >= NN) return;
    int e0 = colptr[n], e1 = colptr[n + 1];
    float h0 = 0.f, h1 = 0.f;
    for (int e = e0 + l; e < e1; e += 8) {
        int src; float w;
        nt_pair(&pairs[e], src, w);
        float2 v = hin[src];
        h0 = fmaf(w, v.x, h0);
        h1 = fmaf(w, v.y, h1);
    }
    h0 += __shfl_xor(h0, 1); h1 += __shfl_xor(h1, 1);
    h0 += __shfl_xor(h0, 2); h1 += __shfl_xor(h1, 2);
    h0 += __shfl_xor(h0, 4); h1 += __shfl_xor(h1, 4);
    if (l == 0) hout[n] = make_float2(h0, h1);
    float2 hm = hin[n];   // h_{k-1} of own node (sequential, broadcast across group)
    int j0 = 2 * l;
    float2* ap = reinterpret_cast<float2*>(acc + (size_t)n * 16 + j0);
    float2 a = *ap;
    a.x = fmaf(h0, sWk[j0],     fmaf(h1, sWk[16 + j0],     a.x));
    a.y = fmaf(h0, sWk[j0 + 1], fmaf(h1, sWk[16 + j0 + 1], a.y));
    a.x = fmaf(hm.x, sWm[j0],     fmaf(hm.y, sWm[16 + j0],     a.x));
    a.y = fmaf(hm.x, sWm[j0 + 1], fmaf(hm.y, sWm[16 + j0 + 1], a.y));
    *ap = a;
}

// relu(acc[N][16] j<15) -> X[N][16], pad 0
__global__ void relu1(const float* __restrict__ acc, float* __restrict__ X) {
    int n = blockIdx.x * 256 + threadIdx.x;
    if (n >= NN) return;
    const float4* ip = reinterpret_cast<const float4*>(acc + (size_t)n * 16);
    float4* op = reinterpret_cast<float4*>(X + (size_t)n * 16);
#pragma unroll
    for (int q = 0; q < 4; q++) {
        float4 v = ip[q];
        v.x = fmaxf(v.x, 0.f); v.y = fmaxf(v.y, 0.f);
        v.z = fmaxf(v.z, 0.f); v.w = fmaxf(v.w, 0.f);
        if (q == 3) v.w = 0.f;
        op[q] = v;
    }
}

// ---------------- layer 2: 15 -> 30, forward, LG=8 feature-split ----------------

__launch_bounds__(256)
__global__ void init_acc2(const float* __restrict__ X, const float* __restrict__ W2,
                          const float* __restrict__ b2, float4* __restrict__ acc) {
    __shared__ float sW[480];  // [15][32] padded
    __shared__ float sb[32];
    int t = threadIdx.x;
    for (int q = t; q < 480; q += 256) {
        int f = q >> 5, j = q & 31;
        sW[q] = (j < 30) ? W2[f * 30 + j] : 0.f;
    }
    if (t < 32) sb[t] = (t < 30) ? b2[t] : 0.f;
    __syncthreads();
    int n = blockIdx.x * 256 + t;
    if (n >= NN) return;
    float h[15];
#pragma unroll
    for (int f = 0; f < 15; f++) h[f] = X[(size_t)n * 16 + f];
#pragma unroll
    for (int q = 0; q < 8; q++) {
        float4 a = make_float4(sb[4*q], sb[4*q+1], sb[4*q+2], sb[4*q+3]);
#pragma unroll
        for (int f = 0; f < 15; f++) {
            float hf = h[f];
            a.x = fmaf(hf, sW[f*32 + 4*q + 0], a.x);
            a.y = fmaf(hf, sW[f*32 + 4*q + 1], a.y);
            a.z = fmaf(hf, sW[f*32 + 4*q + 2], a.z);
            a.w = fmaf(hf, sW[f*32 + 4*q + 3], a.w);
        }
        acc[(size_t)n * 8 + q] = a;
    }
}

// propagate only (odd k) — no LDS, no barrier
__launch_bounds__(256)
__global__ void step2_prop(const int2* __restrict__ pairs, const int* __restrict__ colptr,
                           const float* __restrict__ hin, float* __restrict__ hout) {
    int t = threadIdx.x;
    int g = t >> 3, lane = t & 7;
    int n = blockIdx.x * 32 + g;
    if (n >= NN) return;
    float h0 = 0.f, h1 = 0.f;
    int e0 = colptr[n], e1 = colptr[n + 1];
    const float* hb = hin + 2 * lane;
    int e = e0;
    for (; e + 4 <= e1; e += 4) {
        int s0, s1, s2, s3; float w0, w1, w2, w3;
        nt_pair(&pairs[e + 0], s0, w0);
        nt_pair(&pairs[e + 1], s1, w1);
        nt_pair(&pairs[e + 2], s2, w2);
        nt_pair(&pairs[e + 3], s3, w3);
        float2 v0 = *reinterpret_cast<const float2*>(hb + (size_t)s0 * 16);
        float2 v1 = *reinterpret_cast<const float2*>(hb + (size_t)s1 * 16);
        float2 v2 = *reinterpret_cast<const float2*>(hb + (size_t)s2 * 16);
        float2 v3 = *reinterpret_cast<const float2*>(hb + (size_t)s3 * 16);
        h0 = fmaf(w0, v0.x, h0); h1 = fmaf(w0, v0.y, h1);
        h0 = fmaf(w1, v1.x, h0); h1 = fmaf(w1, v1.y, h1);
        h0 = fmaf(w2, v2.x, h0); h1 = fmaf(w2, v2.y, h1);
        h0 = fmaf(w3, v3.x, h0); h1 = fmaf(w3, v3.y, h1);
    }
    for (; e < e1; e++) {
        int s; float w;
        nt_pair(&pairs[e], s, w);
        float2 v = *reinterpret_cast<const float2*>(hb + (size_t)s * 16);
        h0 = fmaf(w, v.x, h0);
        h1 = fmaf(w, v.y, h1);
    }
    *reinterpret_cast<float2*>(hout + (size_t)n * 16 + 2 * lane) = make_float2(h0, h1);
}

// propagate + double acc (even k): Wpair -> W_{k-1}, W_k contiguous (+450)
__launch_bounds__(256)
__global__ void step2_acc(const int2* __restrict__ pairs, const int* __restrict__ colptr,
                          const float* __restrict__ hin, float* __restrict__ hout,
                          float4* __restrict__ acc, const float* __restrict__ Wpair) {
    __shared__ float sWm[480], sWk[480];   // [15][32] padded cols
    __shared__ float shm[32][17], shk[32][17];
    int t = threadIdx.x;
    for (int q = t; q < 480; q += 256) {
        int f = q >> 5, j = q & 31;
        sWm[q] = (j < 30) ? Wpair[f * 30 + j] : 0.f;
        sWk[q] = (j < 30) ? Wpair[450 + f * 30 + j] : 0.f;
    }
    __syncthreads();
    int g = t >> 3, lane = t & 7;
    int n = blockIdx.x * 32 + g;
    if (n >= NN) return;
    float h0 = 0.f, h1 = 0.f;
    int e0 = colptr[n], e1 = colptr[n + 1];
    const float* hb = hin + 2 * lane;
    int e = e0;
    for (; e + 4 <= e1; e += 4) {
        int s0, s1, s2, s3; float w0, w1, w2, w3;
        nt_pair(&pairs[e + 0], s0, w0);
        nt_pair(&pairs[e + 1], s1, w1);
        nt_pair(&pairs[e + 2], s2, w2);
        nt_pair(&pairs[e + 3], s3, w3);
        float2 v0 = *reinterpret_cast<const float2*>(hb + (size_t)s0 * 16);
        float2 v1 = *reinterpret_cast<const float2*>(hb + (size_t)s1 * 16);
        float2 v2 = *reinterpret_cast<const float2*>(hb + (size_t)s2 * 16);
        float2 v3 = *reinterpret_cast<const float2*>(hb + (size_t)s3 * 16);
        h0 = fmaf(w0, v0.x, h0); h1 = fmaf(w0, v0.y, h1);
        h0 = fmaf(w1, v1.x, h0); h1 = fmaf(w1, v1.y, h1);
        h0 = fmaf(w2, v2.x, h0); h1 = fmaf(w2, v2.y, h1);
        h0 = fmaf(w3, v3.x, h0); h1 = fmaf(w3, v3.y, h1);
    }
    for (; e < e1; e++) {
        int s; float w;
        nt_pair(&pairs[e], s, w);
        float2 v = *reinterpret_cast<const float2*>(hb + (size_t)s * 16);
        h0 = fmaf(w, v.x, h0);
        h1 = fmaf(w, v.y, h1);
    }
    *reinterpret_cast<float2*>(hout + (size_t)n * 16 + 2 * lane) = make_float2(h0, h1);
    // own h_{k-1} slice (sequential read of hin)
    float2 hm = *reinterpret_cast<const float2*>(hin + (size_t)n * 16 + 2 * lane);
    shk[g][2 * lane] = h0;  shk[g][2 * lane + 1] = h1;
    shm[g][2 * lane] = hm.x; shm[g][2 * lane + 1] = hm.y;   // same-wave LDS
    __builtin_amdgcn_wave_barrier();
    float4 a = acc[(size_t)n * 8 + lane];
#pragma unroll
    for (int f = 0; f < 15; f++) {
        float hk = shk[g][f];
        float hmf = shm[g][f];
        a.x = fmaf(hk, sWk[f*32 + 4*lane + 0], fmaf(hmf, sWm[f*32 + 4*lane + 0], a.x));
        a.y = fmaf(hk, sWk[f*32 + 4*lane + 1], fmaf(hmf, sWm[f*32 + 4*lane + 1], a.y));
        a.z = fmaf(hk, sWk[f*32 + 4*lane + 2], fmaf(hmf, sWm[f*32 + 4*lane + 2], a.z));
        a.w = fmaf(hk, sWk[f*32 + 4*lane + 3], fmaf(hmf, sWm[f*32 + 4*lane + 3], a.w));
    }
    acc[(size_t)n * 8 + lane] = a;
}

// relu(acc[N][32] j<30) -> X3[N][32], pad 0
__global__ void relu2(const float4* __restrict__ acc, float4* __restrict__ X3) {
    int n = blockIdx.x * 256 + threadIdx.x;
    if (n >= NN) return;
#pragma unroll
    for (int q = 0; q < 8; q++) {
        float4 v = acc[(size_t)n * 8 + q];
        v.x = fmaxf(v.x, 0.f); v.y = fmaxf(v.y, 0.f);
        v.z = fmaxf(v.z, 0.f); v.w = fmaxf(v.w, 0.f);
        if (q == 7) { v.z = 0.f; v.w = 0.f; }
        X3[(size_t)n * 8 + q] = v;
    }
}

// ---------------- layer 3: 30 -> 15, Horner (propagate 15 cols) ----------------
// r = z_50; for k=49..0: r = z_k + A r;  z_k = X3 @ W3[k]

__launch_bounds__(256)
__global__ void init3(const float* __restrict__ X3, const float* __restrict__ Wk,
                      float* __restrict__ rout) {
    __shared__ float sW[480];  // [30][16] padded col 15 = 0
    int t = threadIdx.x;
    for (int q = t; q < 480; q += 256) {
        int f = q >> 4, j = q & 15;
        sW[q] = (j < 15) ? Wk[f * 15 + j] : 0.f;
    }
    __syncthreads();
    int n = blockIdx.x * 256 + t;
    if (n >= NN) return;
    float h[30];
#pragma unroll
    for (int f = 0; f < 30; f++) h[f] = X3[(size_t)n * 32 + f];
    float z[16];
#pragma unroll
    for (int j = 0; j < 16; j++) z[j] = 0.f;
#pragma unroll
    for (int f = 0; f < 30; f++) {
        float hf = h[f];
#pragma unroll
        for (int j = 0; j < 15; j++) z[j] = fmaf(hf, sW[f*16 + j], z[j]);
    }
    float4* o = reinterpret_cast<float4*>(rout + (size_t)n * 16);
#pragma unroll
    for (int q = 0; q < 4; q++) o[q] = make_float4(z[4*q], z[4*q+1], z[4*q+2], z[4*q+3]);
}

__launch_bounds__(256)
__global__ void step3(const int2* __restrict__ pairs, const int* __restrict__ colptr,
                      const float* __restrict__ rin, float* __restrict__ rout,
                      const float* __restrict__ h0g, const float* __restrict__ Wk) {
    __shared__ float sW[480];     // [30][16] padded col15=0
    __shared__ float sh[32][33];  // h0 rows, padded
    int t = threadIdx.x;
    for (int q = t; q < 480; q += 256) {
        int f = q >> 4, j = q & 15;
        sW[q] = (j < 15) ? Wk[f * 15 + j] : 0.f;
    }
    __syncthreads();
    int g = t >> 3, lane = t & 7;
    int n = blockIdx.x * 32 + g;
    if (n >= NN) return;
    // stage h0 row (sequential, cached across steps)
    float4 hv = *reinterpret_cast<const float4*>(h0g + (size_t)n * 32 + 4 * lane);
    sh[g][4*lane + 0] = hv.x; sh[g][4*lane + 1] = hv.y;
    sh[g][4*lane + 2] = hv.z; sh[g][4*lane + 3] = hv.w;
    __builtin_amdgcn_wave_barrier();
    // z for this lane's two columns
    int j0 = 2 * lane;
    float z0 = 0.f, z1 = 0.f;
#pragma unroll
    for (int f = 0; f < 30; f++) {
        float hf = sh[g][f];
        z0 = fmaf(hf, sW[f*16 + j0], z0);
        z1 = fmaf(hf, sW[f*16 + j0 + 1], z1);
    }
    // gather A·r, 4-deep software pipeline
    int e0 = colptr[n], e1 = colptr[n + 1];
    const float* rb = rin + j0;
    int e = e0;
    for (; e + 4 <= e1; e += 4) {
        int s0, s1, s2, s3; float w0, w1, w2, w3;
        nt_pair(&pairs[e + 0], s0, w0);
        nt_pair(&pairs[e + 1], s1, w1);
        nt_pair(&pairs[e + 2], s2, w2);
        nt_pair(&pairs[e + 3], s3, w3);
        float2 v0 = *reinterpret_cast<const float2*>(rb + (size_t)s0 * 16);
        float2 v1 = *reinterpret_cast<const float2*>(rb + (size_t)s1 * 16);
        float2 v2 = *reinterpret_cast<const float2*>(rb + (size_t)s2 * 16);
        float2 v3 = *reinterpret_cast<const float2*>(rb + (size_t)s3 * 16);
        z0 = fmaf(w0, v0.x, z0); z1 = fmaf(w0, v0.y, z1);
        z0 = fmaf(w1, v1.x, z0); z1 = fmaf(w1, v1.y, z1);
        z0 = fmaf(w2, v2.x, z0); z1 = fmaf(w2, v2.y, z1);
        z0 = fmaf(w3, v3.x, z0); z1 = fmaf(w3, v3.y, z1);
    }
    for (; e < e1; e++) {
        int s; float w;
        nt_pair(&pairs[e], s, w);
        float2 v = *reinterpret_cast<const float2*>(rb + (size_t)s * 16);
        z0 = fmaf(w, v.x, z0);
        z1 = fmaf(w, v.y, z1);
    }
    *reinterpret_cast<float2*>(rout + (size_t)n * 16 + j0) = make_float2(z0, z1);
}

// X4 = relu(r + b3), [N][16] pad 0
__global__ void relu3(const float* __restrict__ r, const float* __restrict__ b3,
                      float* __restrict__ X4) {
    __shared__ float sb[16];
    int t = threadIdx.x;
    if (t < 16) sb[t] = (t < 15) ? b3[t] : 0.f;
    __syncthreads();
    int n = blockIdx.x * 256 + t;
    if (n >= NN) return;
#pragma unroll
    for (int j = 0; j < 16; j++) {
        float v = (j < 15) ? fmaxf(r[(size_t)n * 16 + j] + sb[j], 0.f) : 0.f;
        X4[(size_t)n * 16 + j] = v;
    }
}

// ---------------- layer 4: 15 -> 1, Horner, 8-lane edge-split ----------------

__launch_bounds__(256)
__global__ void init4(const float* __restrict__ X4, const float* __restrict__ Wk,
                      float* __restrict__ rout) {
    __shared__ float sW[16];
    int t = threadIdx.x;
    if (t < 16) sW[t] = (t < 15) ? Wk[t] : 0.f;
    __syncthreads();
    int n = blockIdx.x * 256 + t;
    if (n >= NN) return;
    float z = 0.f;
#pragma unroll
    for (int f = 0; f < 15; f++) z = fmaf(X4[(size_t)n * 16 + f], sW[f], z);
    rout[n] = z;
}

__launch_bounds__(256)
__global__ void step4(const int2* __restrict__ pairs, const int* __restrict__ colptr,
                      const float* __restrict__ rin, float* __restrict__ rout,
                      const float* __restrict__ h0g, const float* __restrict__ Wk) {
    __shared__ float sW[16];
    int t = threadIdx.x;
    if (t < 16) sW[t] = (t < 15) ? Wk[t] : 0.f;
    __syncthreads();
    int g = t >> 3, l = t & 7;
    int n = blockIdx.x * 32 + g;
    if (n >= NN) return;
    // dot partial: lane owns cols [2l, 2l+1] of the X4 row
    int j0 = 2 * l;
    float2 xv = *reinterpret_cast<const float2*>(h0g + (size_t)n * 16 + j0);
    float z = fmaf(xv.x, sW[j0], xv.y * sW[j0 + 1]);
    // gather partial, edges split across 8 lanes
    int e0 = colptr[n], e1 = colptr[n + 1];
    for (int e = e0 + l; e < e1; e += 8) {
        int s; float w;
        nt_pair(&pairs[e], s, w);
        z = fmaf(w, rin[s], z);
    }
    z += __shfl_xor(z, 1);
    z += __shfl_xor(z, 2);
    z += __shfl_xor(z, 4);
    if (l == 0) rout[n] = z;
}

__global__ void out4(const float* __restrict__ r, const float* __restrict__ b4,
                     float* __restrict__ out) {
    int n = blockIdx.x * 256 + threadIdx.x;
    if (n < NN) out[n] = fmaxf(r[n] + b4[0], 0.f);
}

// ---------------- host driver ----------------

extern "C" void kernel_launch(void* const* d_in, const int* in_sizes, int n_in,
                              void* d_out, int out_size, void* d_ws, size_t ws_size,
                              hipStream_t stream) {
    const int*   ei = (const int*)d_in[0];
    const float* ew = (const float*)d_in[1];
    const float* c  = (const float*)d_in[2];
    const int*   ip = (const int*)d_in[3];
    const float* W1 = (const float*)d_in[4];  const float* b1 = (const float*)d_in[5];
    const float* W2 = (const float*)d_in[6];  const float* b2 = (const float*)d_in[7];
    const float* W3 = (const float*)d_in[8];  const float* b3 = (const float*)d_in[9];
    const float* W4 = (const float*)d_in[10]; const float* b4 = (const float*)d_in[11];
    float* out = (float*)d_out;

    char* ws = (char*)d_ws;
    size_t off = 0;
    auto alloc = [&](size_t bytes) -> char* {
        char* p = ws + off;
        off = (off + bytes + 255) & ~(size_t)255;
        return p;
    };
    // persistent
    int2*  pairs  = (int2*)alloc((size_t)NE * 8);              // 12.8 MB
    int*   colptr = (int*)alloc((size_t)(NN + 1) * 4);
    int*   bsum   = (int*)alloc(512 * 4);
    float* HA     = (float*)alloc((size_t)NN * 16 * 4);        // 6.4 MB
    float* HB     = (float*)alloc((size_t)NN * 16 * 4);        // 6.4 MB
    char*  accR   = alloc((size_t)NN * 32 * 4);                // 12.8 MB (ACC | RA,RB)
    char*  x3R    = alloc((size_t)NN * 32 * 4);                // 12.8 MB (X3 | rank,cnt,dis)
    char*  x4R    = alloc((size_t)NN * 16 * 4);                // 6.4 MB  (X4 | X1)

    float*  ACC = (float*)accR;
    float*  RA  = (float*)accR;
    float*  RB  = (float*)(accR + (size_t)NN * 4);
    float*  X3  = (float*)x3R;
    int*    rank = (int*)x3R;                                  // preproc only
    int*    cnt  = (int*)(x3R + (size_t)NE * 4);
    float*  dis  = (float*)(x3R + (size_t)NE * 4 + (size_t)NN * 4);
    float*  X4  = (float*)x4R;
    float2* X1  = (float2*)x4R;                                // layer-1 only

    // ---- preprocessing ----
    zero_kernel<<<NB_N, 256, 0, stream>>>(cnt);
    edge_pass1<<<NB_E, 256, 0, stream>>>(ei, cnt, rank);
    scan_block<<<NB_N, 256, 0, stream>>>(cnt, colptr, bsum);
    scan_top<<<1, 512, 0, stream>>>(bsum, NB_N);
    scan_add<<<NB_N, 256, 0, stream>>>(colptr, bsum);
    scatter_kernel<<<NB_E, 256, 0, stream>>>(ei, ew, colptr, rank, pairs);
    deg_dis_kernel<<<NB_N, 256, 0, stream>>>(pairs, colptr, dis);
    rescale_kernel<<<NB_N, 256, 0, stream>>>(pairs, colptr, dis);
    build_x<<<NB_N, 256, 0, stream>>>(c, ip, X1);

    // ---- layer 1: 2 -> 15 forward ----
    init_acc1<<<NB_N, 256, 0, stream>>>(X1, W1, b1, ACC);
    {
        const float2* hin = X1;
        float2* hout = (float2*)HA;
        for (int k = 1; k <= 50; k++) {
            if (k & 1) {
                step1_prop<<<NB_G, 256, 0, stream>>>(pairs, colptr, hin, hout);
            } else {
                step1_acc<<<NB_G, 256, 0, stream>>>(pairs, colptr, hin, hout, ACC,
                                                    W1 + (size_t)(k - 1) * 30);
            }
            hin = hout;
            hout = (hout == (float2*)HA) ? (float2*)HB : (float2*)HA;
        }
    }
    relu1<<<NB_N, 256, 0, stream>>>(ACC, HA);

    // ---- layer 2: 15 -> 30 forward ----
    init_acc2<<<NB_N, 256, 0, stream>>>(HA, W2, b2, (float4*)ACC);
    {
        const float* hin = HA;
        float* hout = HB;
        for (int k = 1; k <= 50; k++) {
            if (k & 1) {
                step2_prop<<<NB_G, 256, 0, stream>>>(pairs, colptr, hin, hout);
            } else {
                step2_acc<<<NB_G, 256, 0, stream>>>(pairs, colptr, hin, hout, (float4*)ACC,
                                                    W2 + (size_t)(k - 1) * 450);
            }
            const float* tp = hin; hin = hout; hout = (float*)tp;
        }
    }
    relu2<<<NB_N, 256, 0, stream>>>((const float4*)ACC, (float4*)X3);

    // ---- layer 3: 30 -> 15 Horner ----
    init3<<<NB_N, 256, 0, stream>>>(X3, W3 + (size_t)50 * 450, HA);
    {
        const float* rin = HA;
        float* rout = HB;
        for (int k = 49; k >= 0; k--) {
            step3<<<NB_G, 256, 0, stream>>>(pairs, colptr, rin, rout, X3, W3 + (size_t)k * 450);
            const float* tp = rin; rin = rout; rout = (float*)tp;
        }
        relu3<<<NB_N, 256, 0, stream>>>(rin, b3, X4);
    }

    // ---- layer 4: 15 -> 1 Horner ----
    init4<<<NB_N, 256, 0, stream>>>(X4, W4 + (size_t)50 * 15, RA);
    {
        const float* rin = RA;
        float* rout = RB;
        for (int k = 49; k >= 0; k--) {
            step4<<<NB_G, 256, 0, stream>>>(pairs, colptr, rin, rout, X4, W4 + (size_t)k * 15);
            const float* tp = rin; rin = rout; rout = (float*)tp;
        }
        out4<<<NB_N, 256, 0, stream>>>(rin, b4, out);
    }
}

// Round 12
// 4039.701 us; speedup vs baseline: 1.2757x; 1.2757x over previous
//
#include <hip/hip_runtime.h>

#define NN 100000
#define NE 1600000
#define NB_N ((NN + 255) / 256)
#define NB_E ((NE + 255) / 256)
#define NB_G ((NN + 31) / 32)   // 8-lane-group kernels: 32 nodes per 256-thr block

// ---------------- preprocessing: CSR build ----------------

__global__ void zero_kernel(int* __restrict__ cnt) {
    int i = blockIdx.x * 256 + threadIdx.x;
    if (i < NN) cnt[i] = 0;
}

__global__ void edge_pass1(const int* __restrict__ ei, int* __restrict__ cnt,
                           int* __restrict__ rank) {
    int e = blockIdx.x * 256 + threadIdx.x;
    if (e < NE) {
        int col = ei[NE + e];
        rank[e] = atomicAdd(&cnt[col], 1);
    }
}

__global__ void scan_block(const int* __restrict__ cnt, int* __restrict__ colptr,
                           int* __restrict__ bsum) {
    __shared__ int s[256];
    int t = threadIdx.x;
    int i = blockIdx.x * 256 + t;
    int v = (i < NN) ? cnt[i] : 0;
    s[t] = v;
    __syncthreads();
    for (int off = 1; off < 256; off <<= 1) {
        int x = (t >= off) ? s[t - off] : 0;
        __syncthreads();
        s[t] += x;
        __syncthreads();
    }
    if (i < NN) colptr[i] = s[t] - v;
    if (t == 255) bsum[blockIdx.x] = s[255];
}

__global__ void scan_top(int* __restrict__ bsum, int nb) {
    __shared__ int s[512];
    int t = threadIdx.x;
    int v = (t < nb) ? bsum[t] : 0;
    s[t] = v;
    __syncthreads();
    for (int off = 1; off < 512; off <<= 1) {
        int x = (t >= off) ? s[t - off] : 0;
        __syncthreads();
        s[t] += x;
        __syncthreads();
    }
    if (t < nb) bsum[t] = s[t] - v;
}

__global__ void scan_add(int* __restrict__ colptr, const int* __restrict__ bsum) {
    int i = blockIdx.x * 256 + threadIdx.x;
    if (i < NN) colptr[i] += bsum[blockIdx.x];
    if (i == 0) colptr[NN] = NE;
}

__global__ void scatter_kernel(const int* __restrict__ ei, const float* __restrict__ ew,
                               const int* __restrict__ colptr, const int* __restrict__ rank,
                               int2* __restrict__ pairs) {
    int e = blockIdx.x * 256 + threadIdx.x;
    if (e < NE) {
        int r = ei[e], col = ei[NE + e];
        pairs[colptr[col] + rank[e]] = make_int2(r, __float_as_int(ew[e]));
    }
}

__global__ void deg_dis_kernel(const int2* __restrict__ pairs, const int* __restrict__ colptr,
                               float* __restrict__ dis) {
    int n = blockIdx.x * 256 + threadIdx.x;
    if (n < NN) {
        int e0 = colptr[n], e1 = colptr[n + 1];
        float d = 0.f;
        for (int e = e0; e < e1; e++) d += __int_as_float(pairs[e].y);
        dis[n] = d > 0.f ? (float)(1.0 / sqrt((double)d)) : 0.f;
    }
}

__global__ void rescale_kernel(int2* __restrict__ pairs, const int* __restrict__ colptr,
                               const float* __restrict__ dis) {
    int n = blockIdx.x * 256 + threadIdx.x;
    if (n < NN) {
        float dn = dis[n];
        int e0 = colptr[n], e1 = colptr[n + 1];
        for (int e = e0; e < e1; e++) {
            int2 p = pairs[e];
            pairs[e] = make_int2(p.x, __float_as_int(dis[p.x] * __int_as_float(p.y) * dn));
        }
    }
}

__global__ void build_x(const float* __restrict__ c, const int* __restrict__ ip,
                        float2* __restrict__ X1) {
    int n = blockIdx.x * 256 + threadIdx.x;
    if (n < NN) {
        float2 v;
        v.x = (n == ip[0]) ? 1.f : 0.f;
        v.y = c[n];
        X1[n] = v;
    }
}

// ---------------- layer 1: 2 -> 15, forward, 8-lane edge-split ----------------

__launch_bounds__(256)
__global__ void init_acc1(const float2* __restrict__ X1, const float* __restrict__ W1,
                          const float* __restrict__ b1, float* __restrict__ acc) {
    __shared__ float sW[30], sb[15];
    int t = threadIdx.x;
    if (t < 30) sW[t] = W1[t];
    if (t < 15) sb[t] = b1[t];
    __syncthreads();
    int n = blockIdx.x * 256 + t;
    if (n >= NN) return;
    float2 x = X1[n];
    float a[16];
#pragma unroll
    for (int j = 0; j < 15; j++) a[j] = fmaf(x.x, sW[j], fmaf(x.y, sW[15 + j], sb[j]));
    a[15] = 0.f;
    float4* o = reinterpret_cast<float4*>(acc + (size_t)n * 16);
#pragma unroll
    for (int q = 0; q < 4; q++) o[q] = make_float4(a[4*q], a[4*q+1], a[4*q+2], a[4*q+3]);
}

// propagate only (odd k): h_k = A h_{k-1}
__launch_bounds__(256)
__global__ void step1_prop(const int2* __restrict__ pairs, const int* __restrict__ colptr,
                           const float2* __restrict__ hin, float2* __restrict__ hout) {
    int t = threadIdx.x;
    int g = t >> 3, l = t & 7;
    int n = blockIdx.x * 32 + g;
    if (n >= NN) return;
    int e0 = colptr[n], e1 = colptr[n + 1];
    float h0 = 0.f, h1 = 0.f;
    for (int e = e0 + l; e < e1; e += 8) {
        int2 p = pairs[e];
        float w = __int_as_float(p.y);
        float2 v = hin[p.x];
        h0 = fmaf(w, v.x, h0);
        h1 = fmaf(w, v.y, h1);
    }
    h0 += __shfl_xor(h0, 1); h1 += __shfl_xor(h1, 1);
    h0 += __shfl_xor(h0, 2); h1 += __shfl_xor(h1, 2);
    h0 += __shfl_xor(h0, 4); h1 += __shfl_xor(h1, 4);
    if (l == 0) hout[n] = make_float2(h0, h1);
}

// propagate + double acc update (even k): acc += h_{k-1} W_{k-1} + h_k W_k
// Wpair points at W_{k-1}; W_k follows contiguously (+30).
__launch_bounds__(256)
__global__ void step1_acc(const int2* __restrict__ pairs, const int* __restrict__ colptr,
                          const float2* __restrict__ hin, float2* __restrict__ hout,
                          float* __restrict__ acc, const float* __restrict__ Wpair) {
    __shared__ float sWm[32], sWk[32];  // [2][16] padded, col 15 = 0
    int t = threadIdx.x;
    if (t < 32) {
        int f = t >> 4, j = t & 15;
        sWm[t] = (j < 15) ? Wpair[f * 15 + j] : 0.f;
        sWk[t] = (j < 15) ? Wpair[30 + f * 15 + j] : 0.f;
    }
    __syncthreads();
    int g = t >> 3, l = t & 7;
    int n = blockIdx.x * 32 + g;
    if (n >= NN) return;
    int e0 = colptr[n], e1 = colptr[n + 1];
    float h0 = 0.f, h1 = 0.f;
    for (int e = e0 + l; e < e1; e += 8) {
        int2 p = pairs[e];
        float w = __int_as_float(p.y);
        float2 v = hin[p.x];
        h0 = fmaf(w, v.x, h0);
        h1 = fmaf(w, v.y, h1);
    }
    h0 += __shfl_xor(h0, 1); h1 += __shfl_xor(h1, 1);
    h0 += __shfl_xor(h0, 2); h1 += __shfl_xor(h1, 2);
    h0 += __shfl_xor(h0, 4); h1 += __shfl_xor(h1, 4);
    if (l == 0) hout[n] = make_float2(h0, h1);
    float2 hm = hin[n];   // h_{k-1} of own node (sequential, broadcast across group)
    int j0 = 2 * l;
    float2* ap = reinterpret_cast<float2*>(acc + (size_t)n * 16 + j0);
    float2 a = *ap;
    a.x = fmaf(h0, sWk[j0],     fmaf(h1, sWk[16 + j0],     a.x));
    a.y = fmaf(h0, sWk[j0 + 1], fmaf(h1, sWk[16 + j0 + 1], a.y));
    a.x = fmaf(hm.x, sWm[j0],     fmaf(hm.y, sWm[16 + j0],     a.x));
    a.y = fmaf(hm.x, sWm[j0 + 1], fmaf(hm.y, sWm[16 + j0 + 1], a.y));
    *ap = a;
}

// relu(acc[N][16] j<15) -> X[N][16], pad 0
__global__ void relu1(const float* __restrict__ acc, float* __restrict__ X) {
    int n = blockIdx.x * 256 + threadIdx.x;
    if (n >= NN) return;
    const float4* ip = reinterpret_cast<const float4*>(acc + (size_t)n * 16);
    float4* op = reinterpret_cast<float4*>(X + (size_t)n * 16);
#pragma unroll
    for (int q = 0; q < 4; q++) {
        float4 v = ip[q];
        v.x = fmaxf(v.x, 0.f); v.y = fmaxf(v.y, 0.f);
        v.z = fmaxf(v.z, 0.f); v.w = fmaxf(v.w, 0.f);
        if (q == 3) v.w = 0.f;
        op[q] = v;
    }
}

// ---------------- layer 2: 15 -> 30, forward, LG=8 feature-split ----------------

__launch_bounds__(256)
__global__ void init_acc2(const float* __restrict__ X, const float* __restrict__ W2,
                          const float* __restrict__ b2, float4* __restrict__ acc) {
    __shared__ float sW[480];  // [15][32] padded
    __shared__ float sb[32];
    int t = threadIdx.x;
    for (int q = t; q < 480; q += 256) {
        int f = q >> 5, j = q & 31;
        sW[q] = (j < 30) ? W2[f * 30 + j] : 0.f;
    }
    if (t < 32) sb[t] = (t < 30) ? b2[t] : 0.f;
    __syncthreads();
    int n = blockIdx.x * 256 + t;
    if (n >= NN) return;
    float h[15];
#pragma unroll
    for (int f = 0; f < 15; f++) h[f] = X[(size_t)n * 16 + f];
#pragma unroll
    for (int q = 0; q < 8; q++) {
        float4 a = make_float4(sb[4*q], sb[4*q+1], sb[4*q+2], sb[4*q+3]);
#pragma unroll
        for (int f = 0; f < 15; f++) {
            float hf = h[f];
            a.x = fmaf(hf, sW[f*32 + 4*q + 0], a.x);
            a.y = fmaf(hf, sW[f*32 + 4*q + 1], a.y);
            a.z = fmaf(hf, sW[f*32 + 4*q + 2], a.z);
            a.w = fmaf(hf, sW[f*32 + 4*q + 3], a.w);
        }
        acc[(size_t)n * 8 + q] = a;
    }
}

// propagate only (odd k) — no LDS, no barrier
__launch_bounds__(256)
__global__ void step2_prop(const int2* __restrict__ pairs, const int* __restrict__ colptr,
                           const float* __restrict__ hin, float* __restrict__ hout) {
    int t = threadIdx.x;
    int g = t >> 3, lane = t & 7;
    int n = blockIdx.x * 32 + g;
    if (n >= NN) return;
    float h0 = 0.f, h1 = 0.f;
    int e0 = colptr[n], e1 = colptr[n + 1];
    const float* hb = hin + 2 * lane;
    int e = e0;
    for (; e + 4 <= e1; e += 4) {
        int2 p0 = pairs[e + 0];
        int2 p1 = pairs[e + 1];
        int2 p2 = pairs[e + 2];
        int2 p3 = pairs[e + 3];
        float2 v0 = *reinterpret_cast<const float2*>(hb + (size_t)p0.x * 16);
        float2 v1 = *reinterpret_cast<const float2*>(hb + (size_t)p1.x * 16);
        float2 v2 = *reinterpret_cast<const float2*>(hb + (size_t)p2.x * 16);
        float2 v3 = *reinterpret_cast<const float2*>(hb + (size_t)p3.x * 16);
        float w0 = __int_as_float(p0.y), w1 = __int_as_float(p1.y);
        float w2 = __int_as_float(p2.y), w3 = __int_as_float(p3.y);
        h0 = fmaf(w0, v0.x, h0); h1 = fmaf(w0, v0.y, h1);
        h0 = fmaf(w1, v1.x, h0); h1 = fmaf(w1, v1.y, h1);
        h0 = fmaf(w2, v2.x, h0); h1 = fmaf(w2, v2.y, h1);
        h0 = fmaf(w3, v3.x, h0); h1 = fmaf(w3, v3.y, h1);
    }
    for (; e < e1; e++) {
        int2 p = pairs[e];
        float w = __int_as_float(p.y);
        float2 v = *reinterpret_cast<const float2*>(hb + (size_t)p.x * 16);
        h0 = fmaf(w, v.x, h0);
        h1 = fmaf(w, v.y, h1);
    }
    *reinterpret_cast<float2*>(hout + (size_t)n * 16 + 2 * lane) = make_float2(h0, h1);
}

// propagate + double acc (even k): Wpair -> W_{k-1}, W_k contiguous (+450)
__launch_bounds__(256)
__global__ void step2_acc(const int2* __restrict__ pairs, const int* __restrict__ colptr,
                          const float* __restrict__ hin, float* __restrict__ hout,
                          float4* __restrict__ acc, const float* __restrict__ Wpair) {
    __shared__ float sWm[480], sWk[480];   // [15][32] padded cols
    __shared__ float shm[32][17], shk[32][17];
    int t = threadIdx.x;
    for (int q = t; q < 480; q += 256) {
        int f = q >> 5, j = q & 31;
        sWm[q] = (j < 30) ? Wpair[f * 30 + j] : 0.f;
        sWk[q] = (j < 30) ? Wpair[450 + f * 30 + j] : 0.f;
    }
    __syncthreads();
    int g = t >> 3, lane = t & 7;
    int n = blockIdx.x * 32 + g;
    if (n >= NN) return;
    float h0 = 0.f, h1 = 0.f;
    int e0 = colptr[n], e1 = colptr[n + 1];
    const float* hb = hin + 2 * lane;
    int e = e0;
    for (; e + 4 <= e1; e += 4) {
        int2 p0 = pairs[e + 0];
        int2 p1 = pairs[e + 1];
        int2 p2 = pairs[e + 2];
        int2 p3 = pairs[e + 3];
        float2 v0 = *reinterpret_cast<const float2*>(hb + (size_t)p0.x * 16);
        float2 v1 = *reinterpret_cast<const float2*>(hb + (size_t)p1.x * 16);
        float2 v2 = *reinterpret_cast<const float2*>(hb + (size_t)p2.x * 16);
        float2 v3 = *reinterpret_cast<const float2*>(hb + (size_t)p3.x * 16);
        float w0 = __int_as_float(p0.y), w1 = __int_as_float(p1.y);
        float w2 = __int_as_float(p2.y), w3 = __int_as_float(p3.y);
        h0 = fmaf(w0, v0.x, h0); h1 = fmaf(w0, v0.y, h1);
        h0 = fmaf(w1, v1.x, h0); h1 = fmaf(w1, v1.y, h1);
        h0 = fmaf(w2, v2.x, h0); h1 = fmaf(w2, v2.y, h1);
        h0 = fmaf(w3, v3.x, h0); h1 = fmaf(w3, v3.y, h1);
    }
    for (; e < e1; e++) {
        int2 p = pairs[e];
        float w = __int_as_float(p.y);
        float2 v = *reinterpret_cast<const float2*>(hb + (size_t)p.x * 16);
        h0 = fmaf(w, v.x, h0);
        h1 = fmaf(w, v.y, h1);
    }
    *reinterpret_cast<float2*>(hout + (size_t)n * 16 + 2 * lane) = make_float2(h0, h1);
    // own h_{k-1} slice (sequential read of hin)
    float2 hm = *reinterpret_cast<const float2*>(hin + (size_t)n * 16 + 2 * lane);
    shk[g][2 * lane] = h0;  shk[g][2 * lane + 1] = h1;
    shm[g][2 * lane] = hm.x; shm[g][2 * lane + 1] = hm.y;   // same-wave LDS
    __builtin_amdgcn_wave_barrier();
    float4 a = acc[(size_t)n * 8 + lane];
#pragma unroll
    for (int f = 0; f < 15; f++) {
        float hk = shk[g][f];
        float hmf = shm[g][f];
        a.x = fmaf(hk, sWk[f*32 + 4*lane + 0], fmaf(hmf, sWm[f*32 + 4*lane + 0], a.x));
        a.y = fmaf(hk, sWk[f*32 + 4*lane + 1], fmaf(hmf, sWm[f*32 + 4*lane + 1], a.y));
        a.z = fmaf(hk, sWk[f*32 + 4*lane + 2], fmaf(hmf, sWm[f*32 + 4*lane + 2], a.z));
        a.w = fmaf(hk, sWk[f*32 + 4*lane + 3], fmaf(hmf, sWm[f*32 + 4*lane + 3], a.w));
    }
    acc[(size_t)n * 8 + lane] = a;
}

// relu(acc[N][32] j<30) -> X3[N][32], pad 0
__global__ void relu2(const float4* __restrict__ acc, float4* __restrict__ X3) {
    int n = blockIdx.x * 256 + threadIdx.x;
    if (n >= NN) return;
#pragma unroll
    for (int q = 0; q < 8; q++) {
        float4 v = acc[(size_t)n * 8 + q];
        v.x = fmaxf(v.x, 0.f); v.y = fmaxf(v.y, 0.f);
        v.z = fmaxf(v.z, 0.f); v.w = fmaxf(v.w, 0.f);
        if (q == 7) { v.z = 0.f; v.w = 0.f; }
        X3[(size_t)n * 8 + q] = v;
    }
}

// ---------------- layer 3: 30 -> 15, Horner (propagate 15 cols) ----------------
// r = z_50; for k=49..0: r = z_k + A r;  z_k = X3 @ W3[k]

__launch_bounds__(256)
__global__ void init3(const float* __restrict__ X3, const float* __restrict__ Wk,
                      float* __restrict__ rout) {
    __shared__ float sW[480];  // [30][16] padded col 15 = 0
    int t = threadIdx.x;
    for (int q = t; q < 480; q += 256) {
        int f = q >> 4, j = q & 15;
        sW[q] = (j < 15) ? Wk[f * 15 + j] : 0.f;
    }
    __syncthreads();
    int n = blockIdx.x * 256 + t;
    if (n >= NN) return;
    float h[30];
#pragma unroll
    for (int f = 0; f < 30; f++) h[f] = X3[(size_t)n * 32 + f];
    float z[16];
#pragma unroll
    for (int j = 0; j < 16; j++) z[j] = 0.f;
#pragma unroll
    for (int f = 0; f < 30; f++) {
        float hf = h[f];
#pragma unroll
        for (int j = 0; j < 15; j++) z[j] = fmaf(hf, sW[f*16 + j], z[j]);
    }
    float4* o = reinterpret_cast<float4*>(rout + (size_t)n * 16);
#pragma unroll
    for (int q = 0; q < 4; q++) o[q] = make_float4(z[4*q], z[4*q+1], z[4*q+2], z[4*q+3]);
}

__launch_bounds__(256)
__global__ void step3(const int2* __restrict__ pairs, const int* __restrict__ colptr,
                      const float* __restrict__ rin, float* __restrict__ rout,
                      const float* __restrict__ h0g, const float* __restrict__ Wk) {
    __shared__ float sW[480];     // [30][16] padded col15=0
    __shared__ float sh[32][33];  // h0 rows, padded
    int t = threadIdx.x;
    for (int q = t; q < 480; q += 256) {
        int f = q >> 4, j = q & 15;
        sW[q] = (j < 15) ? Wk[f * 15 + j] : 0.f;
    }
    __syncthreads();
    int g = t >> 3, lane = t & 7;
    int n = blockIdx.x * 32 + g;
    if (n >= NN) return;
    // stage h0 row (sequential, cached across steps)
    float4 hv = *reinterpret_cast<const float4*>(h0g + (size_t)n * 32 + 4 * lane);
    sh[g][4*lane + 0] = hv.x; sh[g][4*lane + 1] = hv.y;
    sh[g][4*lane + 2] = hv.z; sh[g][4*lane + 3] = hv.w;
    __builtin_amdgcn_wave_barrier();
    // z for this lane's two columns
    int j0 = 2 * lane;
    float z0 = 0.f, z1 = 0.f;
#pragma unroll
    for (int f = 0; f < 30; f++) {
        float hf = sh[g][f];
        z0 = fmaf(hf, sW[f*16 + j0], z0);
        z1 = fmaf(hf, sW[f*16 + j0 + 1], z1);
    }
    // gather A·r, 4-deep software pipeline
    int e0 = colptr[n], e1 = colptr[n + 1];
    const float* rb = rin + j0;
    int e = e0;
    for (; e + 4 <= e1; e += 4) {
        int2 p0 = pairs[e + 0];
        int2 p1 = pairs[e + 1];
        int2 p2 = pairs[e + 2];
        int2 p3 = pairs[e + 3];
        float2 v0 = *reinterpret_cast<const float2*>(rb + (size_t)p0.x * 16);
        float2 v1 = *reinterpret_cast<const float2*>(rb + (size_t)p1.x * 16);
        float2 v2 = *reinterpret_cast<const float2*>(rb + (size_t)p2.x * 16);
        float2 v3 = *reinterpret_cast<const float2*>(rb + (size_t)p3.x * 16);
        float w0 = __int_as_float(p0.y), w1 = __int_as_float(p1.y);
        float w2 = __int_as_float(p2.y), w3 = __int_as_float(p3.y);
        z0 = fmaf(w0, v0.x, z0); z1 = fmaf(w0, v0.y, z1);
        z0 = fmaf(w1, v1.x, z0); z1 = fmaf(w1, v1.y, z1);
        z0 = fmaf(w2, v2.x, z0); z1 = fmaf(w2, v2.y, z1);
        z0 = fmaf(w3, v3.x, z0); z1 = fmaf(w3, v3.y, z1);
    }
    for (; e < e1; e++) {
        int2 p = pairs[e];
        float w = __int_as_float(p.y);
        float2 v = *reinterpret_cast<const float2*>(rb + (size_t)p.x * 16);
        z0 = fmaf(w, v.x, z0);
        z1 = fmaf(w, v.y, z1);
    }
    *reinterpret_cast<float2*>(rout + (size_t)n * 16 + j0) = make_float2(z0, z1);
}

// X4 = relu(r + b3), [N][16] pad 0
__global__ void relu3(const float* __restrict__ r, const float* __restrict__ b3,
                      float* __restrict__ X4) {
    __shared__ float sb[16];
    int t = threadIdx.x;
    if (t < 16) sb[t] = (t < 15) ? b3[t] : 0.f;
    __syncthreads();
    int n = blockIdx.x * 256 + t;
    if (n >= NN) return;
#pragma unroll
    for (int j = 0; j < 16; j++) {
        float v = (j < 15) ? fmaxf(r[(size_t)n * 16 + j] + sb[j], 0.f) : 0.f;
        X4[(size_t)n * 16 + j] = v;
    }
}

// ---------------- layer 4: 15 -> 1, Horner, 8-lane edge-split ----------------

__launch_bounds__(256)
__global__ void init4(const float* __restrict__ X4, const float* __restrict__ Wk,
                      float* __restrict__ rout) {
    __shared__ float sW[16];
    int t = threadIdx.x;
    if (t < 16) sW[t] = (t < 15) ? Wk[t] : 0.f;
    __syncthreads();
    int n = blockIdx.x * 256 + t;
    if (n >= NN) return;
    float z = 0.f;
#pragma unroll
    for (int f = 0; f < 15; f++) z = fmaf(X4[(size_t)n * 16 + f], sW[f], z);
    rout[n] = z;
}

__launch_bounds__(256)
__global__ void step4(const int2* __restrict__ pairs, const int* __restrict__ colptr,
                      const float* __restrict__ rin, float* __restrict__ rout,
                      const float* __restrict__ h0g, const float* __restrict__ Wk) {
    __shared__ float sW[16];
    int t = threadIdx.x;
    if (t < 16) sW[t] = (t < 15) ? Wk[t] : 0.f;
    __syncthreads();
    int g = t >> 3, l = t & 7;
    int n = blockIdx.x * 32 + g;
    if (n >= NN) return;
    // dot partial: lane owns cols [2l, 2l+1] of the X4 row
    int j0 = 2 * l;
    float2 xv = *reinterpret_cast<const float2*>(h0g + (size_t)n * 16 + j0);
    float z = fmaf(xv.x, sW[j0], xv.y * sW[j0 + 1]);
    // gather partial, edges split across 8 lanes
    int e0 = colptr[n], e1 = colptr[n + 1];
    for (int e = e0 + l; e < e1; e += 8) {
        int2 p = pairs[e];
        z = fmaf(__int_as_float(p.y), rin[p.x], z);
    }
    z += __shfl_xor(z, 1);
    z += __shfl_xor(z, 2);
    z += __shfl_xor(z, 4);
    if (l == 0) rout[n] = z;
}

__global__ void out4(const float* __restrict__ r, const float* __restrict__ b4,
                     float* __restrict__ out) {
    int n = blockIdx.x * 256 + threadIdx.x;
    if (n < NN) out[n] = fmaxf(r[n] + b4[0], 0.f);
}

// ---------------- host driver ----------------

extern "C" void kernel_launch(void* const* d_in, const int* in_sizes, int n_in,
                              void* d_out, int out_size, void* d_ws, size_t ws_size,
                              hipStream_t stream) {
    const int*   ei = (const int*)d_in[0];
    const float* ew = (const float*)d_in[1];
    const float* c  = (const float*)d_in[2];
    const int*   ip = (const int*)d_in[3];
    const float* W1 = (const float*)d_in[4];  const float* b1 = (const float*)d_in[5];
    const float* W2 = (const float*)d_in[6];  const float* b2 = (const float*)d_in[7];
    const float* W3 = (const float*)d_in[8];  const float* b3 = (const float*)d_in[9];
    const float* W4 = (const float*)d_in[10]; const float* b4 = (const float*)d_in[11];
    float* out = (float*)d_out;

    char* ws = (char*)d_ws;
    size_t off = 0;
    auto alloc = [&](size_t bytes) -> char* {
        char* p = ws + off;
        off = (off + bytes + 255) & ~(size_t)255;
        return p;
    };
    // persistent
    int2*  pairs  = (int2*)alloc((size_t)NE * 8);              // 12.8 MB
    int*   colptr = (int*)alloc((size_t)(NN + 1) * 4);
    int*   bsum   = (int*)alloc(512 * 4);
    float* HA     = (float*)alloc((size_t)NN * 16 * 4);        // 6.4 MB
    float* HB     = (float*)alloc((size_t)NN * 16 * 4);        // 6.4 MB
    char*  accR   = alloc((size_t)NN * 32 * 4);                // 12.8 MB (ACC | RA,RB)
    char*  x3R    = alloc((size_t)NN * 32 * 4);                // 12.8 MB (X3 | rank,cnt,dis)
    char*  x4R    = alloc((size_t)NN * 16 * 4);                // 6.4 MB  (X4 | X1)

    float*  ACC = (float*)accR;
    float*  RA  = (float*)accR;
    float*  RB  = (float*)(accR + (size_t)NN * 4);
    float*  X3  = (float*)x3R;
    int*    rank = (int*)x3R;                                  // preproc only
    int*    cnt  = (int*)(x3R + (size_t)NE * 4);
    float*  dis  = (float*)(x3R + (size_t)NE * 4 + (size_t)NN * 4);
    float*  X4  = (float*)x4R;
    float2* X1  = (float2*)x4R;                                // layer-1 only

    // ---- preprocessing ----
    zero_kernel<<<NB_N, 256, 0, stream>>>(cnt);
    edge_pass1<<<NB_E, 256, 0, stream>>>(ei, cnt, rank);
    scan_block<<<NB_N, 256, 0, stream>>>(cnt, colptr, bsum);
    scan_top<<<1, 512, 0, stream>>>(bsum, NB_N);
    scan_add<<<NB_N, 256, 0, stream>>>(colptr, bsum);
    scatter_kernel<<<NB_E, 256, 0, stream>>>(ei, ew, colptr, rank, pairs);
    deg_dis_kernel<<<NB_N, 256, 0, stream>>>(pairs, colptr, dis);
    rescale_kernel<<<NB_N, 256, 0, stream>>>(pairs, colptr, dis);
    build_x<<<NB_N, 256, 0, stream>>>(c, ip, X1);

    // ---- layer 1: 2 -> 15 forward ----
    init_acc1<<<NB_N, 256, 0, stream>>>(X1, W1, b1, ACC);
    {
        const float2* hin = X1;
        float2* hout = (float2*)HA;
        for (int k = 1; k <= 50; k++) {
            if (k & 1) {
                step1_prop<<<NB_G, 256, 0, stream>>>(pairs, colptr, hin, hout);
            } else {
                step1_acc<<<NB_G, 256, 0, stream>>>(pairs, colptr, hin, hout, ACC,
                                                    W1 + (size_t)(k - 1) * 30);
            }
            hin = hout;
            hout = (hout == (float2*)HA) ? (float2*)HB : (float2*)HA;
        }
    }
    relu1<<<NB_N, 256, 0, stream>>>(ACC, HA);

    // ---- layer 2: 15 -> 30 forward ----
    init_acc2<<<NB_N, 256, 0, stream>>>(HA, W2, b2, (float4*)ACC);
    {
        const float* hin = HA;
        float* hout = HB;
        for (int k = 1; k <= 50; k++) {
            if (k & 1) {
                step2_prop<<<NB_G, 256, 0, stream>>>(pairs, colptr, hin, hout);
            } else {
                step2_acc<<<NB_G, 256, 0, stream>>>(pairs, colptr, hin, hout, (float4*)ACC,
                                                    W2 + (size_t)(k - 1) * 450);
            }
            const float* tp = hin; hin = hout; hout = (float*)tp;
        }
    }
    relu2<<<NB_N, 256, 0, stream>>>((const float4*)ACC, (float4*)X3);

    // ---- layer 3: 30 -> 15 Horner ----
    init3<<<NB_N, 256, 0, stream>>>(X3, W3 + (size_t)50 * 450, HA);
    {
        const float* rin = HA;
        float* rout = HB;
        for (int k = 49; k >= 0; k--) {
            step3<<<NB_G, 256, 0, stream>>>(pairs, colptr, rin, rout, X3, W3 + (size_t)k * 450);
            const float* tp = rin; rin = rout; rout = (float*)tp;
        }
        relu3<<<NB_N, 256, 0, stream>>>(rin, b3, X4);
    }

    // ---- layer 4: 15 -> 1 Horner ----
    init4<<<NB_N, 256, 0, stream>>>(X4, W4 + (size_t)50 * 15, RA);
    {
        const float* rin = RA;
        float* rout = RB;
        for (int k = 49; k >= 0; k--) {
            step4<<<NB_G, 256, 0, stream>>>(pairs, colptr, rin, rout, X4, W4 + (size_t)k * 15);
            const float* tp = rin; rin = rout; rout = (float*)tp;
        }
        out4<<<NB_N, 256, 0, stream>>>(rin, b4, out);
    }
}